// Round 1
// baseline (574.996 us; speedup 1.0000x reference)
//
#include <hip/hip_runtime.h>

#define HH 480
#define WW 640
#define NPIX (HH * WW)
#define BB 16

__global__ void zero_out_kernel(float* out) {
    if (threadIdx.x == 0) out[0] = 0.0f;
}

__global__ __launch_bounds__(256) void proj_depth_loss_kernel(
    const float* __restrict__ depth0, const float* __restrict__ depth1,
    const float* __restrict__ R0, const float* __restrict__ t0,
    const float* __restrict__ R1, const float* __restrict__ t1,
    const float* __restrict__ Km, const float* __restrict__ ray,
    float* __restrict__ out)
{
    const int pass = blockIdx.z;
    const int b = blockIdx.y;
    const int n = blockIdx.x * blockDim.x + threadIdx.x;

    const float* Ds = (pass == 0) ? depth0 : depth1;
    const float* Dt = (pass == 0) ? depth1 : depth0;
    const float* Ra = (pass == 0) ? R0 : R1;
    const float* ta = (pass == 0) ? t0 : t1;
    const float* Rb = (pass == 0) ? R1 : R0;
    const float* tb = (pass == 0) ? t1 : t0;

    float diff = 0.0f;
    if (n < NPIX) {
        float d = Ds[b * NPIX + n];
        float rx = ray[3 * n + 0];
        float ry = ray[3 * n + 1];
        float rz = ray[3 * n + 2];

        // unproject, subtract t_src
        float x = d * rx - ta[b * 3 + 0];
        float y = d * ry - ta[b * 3 + 1];
        float z = d * rz - ta[b * 3 + 2];

        // v @ R_src  (einsum bnk,bkj->bnj): w_j = sum_k v_k * Ra[k][j]
        const float* A = Ra + b * 9;
        float wx = x * A[0] + y * A[3] + z * A[6];
        float wy = x * A[1] + y * A[4] + z * A[7];
        float wz = x * A[2] + y * A[5] + z * A[8];

        // w @ R_dst^T + t_dst (einsum bnk,bjk->bnj): p_j = w . Rb[j][:]
        const float* Bm = Rb + b * 9;
        float px = wx * Bm[0] + wy * Bm[1] + wz * Bm[2] + tb[b * 3 + 0];
        float py = wx * Bm[3] + wy * Bm[4] + wz * Bm[5] + tb[b * 3 + 1];
        float pz = wx * Bm[6] + wy * Bm[7] + wz * Bm[8] + tb[b * 3 + 2];

        // uvd = p @ K^T
        float ux = Km[0] * px + Km[1] * py + Km[2] * pz;
        float uy = Km[3] * px + Km[4] * py + Km[5] * pz;
        float ud = Km[6] * px + Km[7] * py + Km[8] * pz;

        float denom = fmaxf(ud, 0.0f) + 1e-12f;
        float gx = 2.0f * (ux / denom / (float)(WW - 1) - 0.5f);
        float gy = 2.0f * (uy / denom / (float)(HH - 1) - 0.5f);

        // grid_sample bilinear, border padding, align_corners=False
        float sx = ((gx + 1.0f) * (float)WW - 1.0f) * 0.5f;
        float sy = ((gy + 1.0f) * (float)HH - 1.0f) * 0.5f;
        sx = fminf(fmaxf(sx, 0.0f), (float)(WW - 1));
        sy = fminf(fmaxf(sy, 0.0f), (float)(HH - 1));
        float fx0 = floorf(sx);
        float fy0 = floorf(sy);
        float wxf = sx - fx0;
        float wyf = sy - fy0;
        int x0 = (int)fx0;
        int y0 = (int)fy0;
        int x1 = min(x0 + 1, WW - 1);
        int y1 = min(y0 + 1, HH - 1);

        const float* img = Dt + b * NPIX;
        float v00 = img[y0 * WW + x0];
        float v01 = img[y0 * WW + x1];
        float v10 = img[y1 * WW + x0];
        float v11 = img[y1 * WW + x1];

        float s = (1.0f - wyf) * ((1.0f - wxf) * v00 + wxf * v01)
                +         wyf  * ((1.0f - wxf) * v10 + wxf * v11);
        diff = fabsf(ud - s);
    }

    // wave-64 shuffle reduction
    for (int off = 32; off > 0; off >>= 1)
        diff += __shfl_down(diff, off, 64);

    __shared__ float partial[4];
    const int wave = threadIdx.x >> 6;
    const int lane = threadIdx.x & 63;
    if (lane == 0) partial[wave] = diff;
    __syncthreads();
    if (threadIdx.x == 0) {
        float s = partial[0] + partial[1] + partial[2] + partial[3];
        atomicAdd(out, s * (1.0f / (float)((long long)BB * NPIX)));
    }
}

extern "C" void kernel_launch(void* const* d_in, const int* in_sizes, int n_in,
                              void* d_out, int out_size, void* d_ws, size_t ws_size,
                              hipStream_t stream) {
    const float* depth0 = (const float*)d_in[0];
    const float* depth1 = (const float*)d_in[1];
    const float* R0     = (const float*)d_in[2];
    const float* t0     = (const float*)d_in[3];
    const float* R1     = (const float*)d_in[4];
    const float* t1     = (const float*)d_in[5];
    const float* Km     = (const float*)d_in[6];
    const float* ray    = (const float*)d_in[7];
    float* out = (float*)d_out;

    zero_out_kernel<<<1, 64, 0, stream>>>(out);

    dim3 block(256);
    dim3 grid((NPIX + 255) / 256, BB, 2);
    proj_depth_loss_kernel<<<grid, block, 0, stream>>>(
        depth0, depth1, R0, t0, R1, t1, Km, ray, out);
}

// Round 2
// 121.462 us; speedup vs baseline: 4.7340x; 4.7340x over previous
//
#include <hip/hip_runtime.h>

#define HH 480
#define WW 640
#define NPIX (HH * WW)
#define BB 16
#define PPT 4                      // pixels per thread
#define BLK 256
#define GX (NPIX / (BLK * PPT))    // 300 blocks along pixel dim
#define NPART (GX * BB * 2)        // 9600 block partials

__global__ __launch_bounds__(BLK) void proj_depth_loss_kernel(
    const float* __restrict__ depth0, const float* __restrict__ depth1,
    const float* __restrict__ R0, const float* __restrict__ t0,
    const float* __restrict__ R1, const float* __restrict__ t1,
    const float* __restrict__ Km, const float* __restrict__ ray,
    float* __restrict__ ws)
{
    const int pass = blockIdx.z;
    const int b = blockIdx.y;
    const int n0 = (blockIdx.x * BLK + threadIdx.x) * PPT;

    const float* Ds = (pass == 0) ? depth0 : depth1;
    const float* Dt = (pass == 0) ? depth1 : depth0;
    const float* Ra = (pass == 0) ? R0 : R1;
    const float* ta = (pass == 0) ? t0 : t1;
    const float* Rb = (pass == 0) ? R1 : R0;
    const float* tb = (pass == 0) ? t1 : t0;

    // uniform per-block scalars (b, pass uniform -> scalar loads)
    const float* A = Ra + b * 9;
    const float* Bm = Rb + b * 9;
    float A0=A[0],A1=A[1],A2=A[2],A3=A[3],A4=A[4],A5=A[5],A6=A[6],A7=A[7],A8=A[8];
    float B0=Bm[0],B1=Bm[1],B2=Bm[2],B3=Bm[3],B4=Bm[4],B5=Bm[5],B6=Bm[6],B7=Bm[7],B8=Bm[8];
    float tax=ta[b*3+0], tay=ta[b*3+1], taz=ta[b*3+2];
    float tbx=tb[b*3+0], tby=tb[b*3+1], tbz=tb[b*3+2];
    float K0=Km[0],K1=Km[1],K2=Km[2],K3=Km[3],K4=Km[4],K5=Km[5],K6=Km[6],K7=Km[7],K8=Km[8];

    const float cw = (float)WW / (float)(WW - 1);
    const float ch = (float)HH / (float)(HH - 1);

    // vector loads: depth (4 floats), ray (12 floats)
    float4 d4 = *(const float4*)(Ds + b * NPIX + n0);
    const float4* rp = (const float4*)(ray + 3 * n0);
    float4 ra = rp[0], rbv = rp[1], rc = rp[2];

    float dd[PPT] = {d4.x, d4.y, d4.z, d4.w};
    float rx[PPT] = {ra.x, ra.w, rbv.z, rc.y};
    float ry[PPT] = {ra.y, rbv.x, rbv.w, rc.z};
    float rz[PPT] = {ra.z, rbv.y, rc.x, rc.w};

    float ud[PPT], wxf[PPT], wyf[PPT];
    int i00[PPT], i01[PPT], i10[PPT], i11[PPT];

    #pragma unroll
    for (int i = 0; i < PPT; ++i) {
        float d = dd[i];
        float x = d * rx[i] - tax;
        float y = d * ry[i] - tay;
        float z = d * rz[i] - taz;

        float wx = x * A0 + y * A3 + z * A6;
        float wy = x * A1 + y * A4 + z * A7;
        float wz = x * A2 + y * A5 + z * A8;

        float px = wx * B0 + wy * B1 + wz * B2 + tbx;
        float py = wx * B3 + wy * B4 + wz * B5 + tby;
        float pz = wx * B6 + wy * B7 + wz * B8 + tbz;

        float ux = K0 * px + K1 * py + K2 * pz;
        float uy = K3 * px + K4 * py + K5 * pz;
        float uu = K6 * px + K7 * py + K8 * pz;
        ud[i] = uu;

        float inv = 1.0f / (fmaxf(uu, 0.0f) + 1e-12f);
        float sx = ux * inv * cw - 0.5f;   // == ((gx+1)*W-1)*0.5
        float sy = uy * inv * ch - 0.5f;
        sx = fminf(fmaxf(sx, 0.0f), (float)(WW - 1));
        sy = fminf(fmaxf(sy, 0.0f), (float)(HH - 1));
        float fx0 = floorf(sx);
        float fy0 = floorf(sy);
        wxf[i] = sx - fx0;
        wyf[i] = sy - fy0;
        int x0 = (int)fx0;
        int y0 = (int)fy0;
        int x1 = min(x0 + 1, WW - 1);
        int y1 = min(y0 + 1, HH - 1);
        i00[i] = y0 * WW + x0;
        i01[i] = y0 * WW + x1;
        i10[i] = y1 * WW + x0;
        i11[i] = y1 * WW + x1;
    }

    const float* img = Dt + b * NPIX;
    float v00[PPT], v01[PPT], v10[PPT], v11[PPT];
    #pragma unroll
    for (int i = 0; i < PPT; ++i) {
        v00[i] = img[i00[i]];
        v01[i] = img[i01[i]];
        v10[i] = img[i10[i]];
        v11[i] = img[i11[i]];
    }

    float diff = 0.0f;
    #pragma unroll
    for (int i = 0; i < PPT; ++i) {
        float s = (1.0f - wyf[i]) * ((1.0f - wxf[i]) * v00[i] + wxf[i] * v01[i])
                +         wyf[i]  * ((1.0f - wxf[i]) * v10[i] + wxf[i] * v11[i]);
        diff += fabsf(ud[i] - s);
    }

    // wave-64 shuffle reduction
    for (int off = 32; off > 0; off >>= 1)
        diff += __shfl_down(diff, off, 64);

    __shared__ float partial[BLK / 64];
    const int wave = threadIdx.x >> 6;
    const int lane = threadIdx.x & 63;
    if (lane == 0) partial[wave] = diff;
    __syncthreads();
    if (threadIdx.x == 0) {
        float s = partial[0] + partial[1] + partial[2] + partial[3];
        ws[blockIdx.x + GX * (blockIdx.y + BB * blockIdx.z)] = s;
    }
}

__global__ __launch_bounds__(1024) void reduce_partials_kernel(
    const float* __restrict__ ws, float* __restrict__ out)
{
    float s = 0.0f;
    for (int i = threadIdx.x; i < NPART; i += 1024) s += ws[i];
    for (int off = 32; off > 0; off >>= 1)
        s += __shfl_down(s, off, 64);
    __shared__ float partial[16];
    const int wave = threadIdx.x >> 6;
    const int lane = threadIdx.x & 63;
    if (lane == 0) partial[wave] = s;
    __syncthreads();
    if (threadIdx.x == 0) {
        float tot = 0.0f;
        #pragma unroll
        for (int i = 0; i < 16; ++i) tot += partial[i];
        out[0] = tot * (1.0f / (float)((long long)BB * NPIX));
    }
}

extern "C" void kernel_launch(void* const* d_in, const int* in_sizes, int n_in,
                              void* d_out, int out_size, void* d_ws, size_t ws_size,
                              hipStream_t stream) {
    const float* depth0 = (const float*)d_in[0];
    const float* depth1 = (const float*)d_in[1];
    const float* R0     = (const float*)d_in[2];
    const float* t0     = (const float*)d_in[3];
    const float* R1     = (const float*)d_in[4];
    const float* t1     = (const float*)d_in[5];
    const float* Km     = (const float*)d_in[6];
    const float* ray    = (const float*)d_in[7];
    float* out = (float*)d_out;
    float* ws  = (float*)d_ws;

    dim3 block(BLK);
    dim3 grid(GX, BB, 2);
    proj_depth_loss_kernel<<<grid, block, 0, stream>>>(
        depth0, depth1, R0, t0, R1, t1, Km, ray, ws);
    reduce_partials_kernel<<<1, 1024, 0, stream>>>(ws, out);
}